// Round 2
// 310.640 us; speedup vs baseline: 1.1510x; 1.1510x over previous
//
#include <hip/hip_runtime.h>

typedef unsigned short u16;
typedef unsigned int   u32;
typedef __bf16 bf16x8 __attribute__((ext_vector_type(8)));
typedef float  f32x4  __attribute__((ext_vector_type(4)));

#define DD 1024

__device__ __forceinline__ u16 f2bf(float f) {
  u32 u = __float_as_uint(f);
  u32 r = (u + 0x7FFFu + ((u >> 16) & 1u)) >> 16;
  return (u16)r;
}

// async global->LDS, 16B per lane. Dest must be wave-uniform-base + lane*16.
typedef const __attribute__((address_space(1))) void* gp1;
typedef __attribute__((address_space(3))) void* lp3;
__device__ __forceinline__ void gll16(const void* g, void* l) {
  __builtin_amdgcn_global_load_lds((gp1)g, (lp3)l, 16, 0, 0);
}

// ---------------------------------------------------------------------------
// k01: merged k0f + k1 (they are independent -> run concurrently).
// blocks 0..255   : x fp32 -> bf16 convert (XB) + pooled column sums
// blocks 256..287 : AWBW[16][1024] = {A,B}@W_base (fp32 atomics, split-i)
// blocks 288..291 : Mbuf: 4 Gram 8x8 (A.Us, B.Us, A.Ul, B.Ul)
// blocks 292..295 : Pb[32][1024] = bf16([Ao;Bo;Us;Ul])
// blocks 296..551 : Wt[n][k] = bf16(W[k][n])  (transpose + convert)
// ---------------------------------------------------------------------------
template <bool XB>
__global__ __launch_bounds__(256) void k01_pre(
    const float* __restrict__ x, u16* __restrict__ xb, float* __restrict__ pooled,
    const float* __restrict__ W,
    const float* __restrict__ Ao, const float* __restrict__ Bo,
    const float* __restrict__ Us, const float* __restrict__ Ul,
    float* __restrict__ AWBW, float* __restrict__ Mbuf,
    u16* __restrict__ Pb, u16* __restrict__ Wt) {
  const int tid = threadIdx.x;
  int bid = blockIdx.x;
  if (bid < 256) {
    const int b = bid >> 6;
    const long r0 = (long)bid * 64;
    const int c0 = tid * 4;
    float s0 = 0.f, s1 = 0.f, s2 = 0.f, s3 = 0.f;
    for (int r = 0; r < 64; r++) {
      float4 v = *(const float4*)(x + (r0 + r) * DD + c0);
      if (XB) {
        ushort4 o;
        o.x = f2bf(v.x); o.y = f2bf(v.y); o.z = f2bf(v.z); o.w = f2bf(v.w);
        *(ushort4*)(xb + (r0 + r) * DD + c0) = o;
      }
      s0 += v.x; s1 += v.y; s2 += v.z; s3 += v.w;
    }
    atomicAdd(&pooled[b * DD + c0 + 0], s0);
    atomicAdd(&pooled[b * DD + c0 + 1], s1);
    atomicAdd(&pooled[b * DD + c0 + 2], s2);
    atomicAdd(&pooled[b * DD + c0 + 3], s3);
    return;
  }
  bid -= 256;
  if (bid < 32) {
    __shared__ float red2[2][128][16];
    const int m = bid;
    const int n = (m & 7) * 128 + (tid & 127), q = m >> 3, ih = tid >> 7;
    float acc[16];
#pragma unroll
    for (int k = 0; k < 16; k++) acc[k] = 0.f;
    const int ib = q * 256 + ih * 128;
    for (int i = ib; i < ib + 128; i++) {
      float wv = W[(long)i * DD + n];
#pragma unroll
      for (int k = 0; k < 8; k++) {
        acc[k]     += Ao[k * DD + i] * wv;
        acc[k + 8] += Bo[k * DD + i] * wv;
      }
    }
#pragma unroll
    for (int k = 0; k < 16; k++) red2[ih][tid & 127][k] = acc[k];
    __syncthreads();
    if (ih == 0)
#pragma unroll
      for (int k = 0; k < 16; k++)
        atomicAdd(&AWBW[k * DD + n], red2[0][tid][k] + red2[1][tid][k]);
  } else if (bid < 36) {
    __shared__ float red[64][4];
    const int m = bid - 32;
    const float* L  = (m == 0 || m == 2) ? Ao : Bo;
    const float* Rr = (m < 2) ? Us : Ul;
    const int o = tid >> 2, ch = tid & 3;
    const int k = o >> 3, kp = o & 7;
    float a = 0.f;
    for (int i = ch * 256; i < ch * 256 + 256; i++)
      a += L[(long)k * DD + i] * Rr[(long)kp * DD + i];
    red[o][ch] = a;
    __syncthreads();
    if (tid < 64) Mbuf[m * 64 + tid] = red[tid][0] + red[tid][1] + red[tid][2] + red[tid][3];
  } else if (bid < 40) {
    const int m = bid - 36;
    const float* src = m == 0 ? Ao : m == 1 ? Bo : m == 2 ? Us : Ul;
#pragma unroll
    for (int j = 0; j < 8; j++)
      for (int q = 0; q < 4; q++) {
        int i = q * 256 + tid;
        Pb[(m * 8 + j) * DD + i] = f2bf(src[j * DD + i]);
      }
  } else {
    __shared__ u16 T[64][66];
    const int t = bid - 40, tr = t >> 4, tc = t & 15;
#pragma unroll
    for (int q2 = 0; q2 < 16; q2++) {
      int idx = q2 * 256 + tid, r = idx >> 6, c = idx & 63;
      T[r][c] = f2bf(W[(long)(tr * 64 + r) * DD + tc * 64 + c]);
    }
    __syncthreads();
#pragma unroll
    for (int q2 = 0; q2 < 16; q2++) {
      int idx = q2 * 256 + tid, c = idx >> 6, r = idx & 63;
      Wt[(long)(tc * 64 + c) * DD + tr * 64 + r] = T[r][c];
    }
  }
}

// ---------------------------------------------------------------------------
// k2a: h1pre[b][j] partial = sum_{d in chunk} z[d] * Wc1[d][j].
// ---------------------------------------------------------------------------
__global__ __launch_bounds__(256) void k2a_h1(
    const float* __restrict__ pooledsum,
    const float* __restrict__ lng, const float* __restrict__ lnb,
    const float* __restrict__ Wc1, float* __restrict__ h1pre) {
  __shared__ float zs[1024];
  __shared__ float wsh[16384];
  __shared__ float red[256];
  const int tid = threadIdx.x;
  const int b = blockIdx.x >> 3, ch = blockIdx.x & 7;
  float4 v = *(const float4*)(pooledsum + b * DD + tid * 4);
  v.x *= (1.f / 4096.f); v.y *= (1.f / 4096.f); v.z *= (1.f / 4096.f); v.w *= (1.f / 4096.f);
  float s = v.x + v.y + v.z + v.w;
  float sq = v.x * v.x + v.y * v.y + v.z * v.z + v.w * v.w;
  red[tid] = s; __syncthreads();
  for (int st = 128; st > 0; st >>= 1) { if (tid < st) red[tid] += red[tid + st]; __syncthreads(); }
  float mu = red[0] * (1.f / 1024.f);
  __syncthreads();
  red[tid] = sq; __syncthreads();
  for (int st = 128; st > 0; st >>= 1) { if (tid < st) red[tid] += red[tid + st]; __syncthreads(); }
  float var = red[0] * (1.f / 1024.f) - mu * mu;
  float rs = rsqrtf(var + 1e-5f);
  __syncthreads();
  {
    float4 g = *(const float4*)(lng + tid * 4);
    float4 be = *(const float4*)(lnb + tid * 4);
    zs[tid * 4 + 0] = (v.x - mu) * rs * g.x + be.x;
    zs[tid * 4 + 1] = (v.y - mu) * rs * g.y + be.y;
    zs[tid * 4 + 2] = (v.z - mu) * rs * g.z + be.z;
    zs[tid * 4 + 3] = (v.w - mu) * rs * g.w + be.w;
  }
  {
    const float4* src = (const float4*)(Wc1 + ch * 16384);
    float4* dst = (float4*)wsh;
#pragma unroll
    for (int it = 0; it < 16; it++) dst[it * 256 + tid] = src[it * 256 + tid];
  }
  __syncthreads();
  const int j = tid & 127, half = tid >> 7;
  float a = 0.f;
#pragma unroll 8
  for (int dd = 0; dd < 64; dd++) {
    int ldi = half * 64 + dd;
    a += zs[ch * 128 + ldi] * wsh[ldi * 128 + j];
  }
  red[tid] = a;
  __syncthreads();
  if (tid < 128) atomicAdd(&h1pre[b * 128 + tid], red[tid] + red[tid + 128]);
}

// ---------------------------------------------------------------------------
// k2b: blocks 0..3: gelu(h1pre+bc1) @ Wc2 + bc2 -> heads -> gates[b][24]
//      blocks 4..7: pack RwT[n][32] = bf16{AW(8) BW(8) Vs(8) Vl(8)}(., n)
// ---------------------------------------------------------------------------
__global__ __launch_bounds__(256) void k2b_gates_pack(
    const float* __restrict__ h1pre, const float* __restrict__ AWBW,
    const float* Vs, const float* Vl,
    const float* bc1, const float* Wc2, const float* bc2,
    const float* Wrg, const float* brg, const float* Wrc, const float* brc,
    const float* Wsg, const float* bsg, const float* Wlc, const float* blc,
    float* __restrict__ gates, u16* __restrict__ RwT) {
  const int tid = threadIdx.x;
  if (blockIdx.x < 4) {
    __shared__ float wc2sh[16384];
    __shared__ float h1s[128], hb[128];
    __shared__ float red[256];
    __shared__ float hw[3200];
    const int b = blockIdx.x;
    {
      const float4* src = (const float4*)Wc2;
      float4* dst = (float4*)wc2sh;
#pragma unroll
      for (int it = 0; it < 16; it++) dst[it * 256 + tid] = src[it * 256 + tid];
    }
    for (int idx = tid; idx < 3200; idx += 256) {
      float vv;
      if (idx < 128)       vv = Wrg[idx];
      else if (idx < 1152) vv = Wrc[idx - 128];
      else if (idx < 2176) vv = Wsg[idx - 1152];
      else                 vv = Wlc[idx - 2176];
      hw[idx] = vv;
    }
    if (tid < 128) {
      float hv = h1pre[b * 128 + tid] + bc1[tid];
      float th = tanhf(0.7978845608028654f * (hv + 0.044715f * hv * hv * hv));
      h1s[tid] = 0.5f * hv * (1.f + th);
    }
    __syncthreads();
    const int i = tid & 127, half = tid >> 7;
    float a = 0.f;
#pragma unroll 8
    for (int k = 0; k < 64; k++) {
      int kk = half * 64 + k;
      a += h1s[kk] * wc2sh[kk * 128 + i];
    }
    red[tid] = a;
    __syncthreads();
    if (tid < 128) hb[tid] = red[tid] + red[tid + 128] + bc2[tid];
    __syncthreads();
    if (tid < 25) {
      float acc;
      if (tid == 0) {
        acc = brg[0];
        for (int k = 0; k < 128; k++) acc += hb[k] * hw[k];
        red[0] = 1.f / (1.f + expf(-acc));
      } else if (tid < 9) {
        int ci = tid - 1; acc = brc[ci];
        for (int k = 0; k < 128; k++) acc += hb[k] * hw[128 + k * 8 + ci];
        red[tid] = tanhf(acc);
      } else if (tid < 17) {
        int ci = tid - 9; acc = bsg[ci];
        for (int k = 0; k < 128; k++) acc += hb[k] * hw[1152 + k * 8 + ci];
        red[tid] = tanhf(acc);
      } else {
        int ci = tid - 17; acc = blc[ci];
        for (int k = 0; k < 128; k++) acc += hb[k] * hw[2176 + k * 8 + ci];
        red[tid] = tanhf(acc);
      }
    }
    __syncthreads();
    if (tid < 24) {
      float g = red[0];
      gates[b * 32 + tid] = (tid < 8) ? g * red[1 + tid] : red[1 + tid];
    }
  } else {
    const int n = (int)(blockIdx.x - 4) * 256 + tid;
#pragma unroll
    for (int j = 0; j < 8; j++) {
      RwT[n * 32 + j]      = f2bf(AWBW[j * DD + n]);
      RwT[n * 32 + 8 + j]  = f2bf(AWBW[(8 + j) * DD + n]);
      RwT[n * 32 + 16 + j] = f2bf(Vs[(long)j * DD + n]);
      RwT[n * 32 + 24 + j] = f2bf(Vl[(long)j * DD + n]);
    }
  }
}

// ---------------------------------------------------------------------------
// k3a (mode A): fused GEMM, double-buffered LDS via global_load_lds (16B),
// ONE barrier per K-chunk. Integer byte offsets into a single smem blob
// (pointer-array init of LDS addresses is rejected by the gfx950 backend).
// LDS map (bytes): A0 0..8K, A1 8..16K, B0 16..24K, B1 24..32K,
// P0 32768..34816, P1 34816..36864, Ml 36864, gl 37888.
// After main loop: projF overlays A0+A1, wLds overlays B1, RwT tile -> B0.
// ---------------------------------------------------------------------------
__global__ __launch_bounds__(256, 3) void k3a_fused(
    const u16* __restrict__ xb, const u16* __restrict__ Wt,
    const u16* __restrict__ Pb, const float* __restrict__ gates,
    const float* __restrict__ Mbuf, const u16* __restrict__ RwT,
    const float* __restrict__ bb, float* __restrict__ out) {
  __shared__ __align__(16) char smem[38912];
  const int tid = threadIdx.x, lane = tid & 63, w = tid >> 6;
  const int quad = lane >> 4, lrow = lane & 15;
  const int bn = blockIdx.x & 7, bm = blockIdx.x >> 3;
  const long m0 = (long)bm * 128;
  const int n0 = bn * 128;
  const int batch = bm >> 5;
  float* Ml = (float*)(smem + 36864);
  float* gl = (float*)(smem + 37888);
  Ml[tid] = Mbuf[tid];
  if (tid < 24) gl[tid] = gates[batch * 32 + tid];
  const int mw = (w & 1) * 64, nw = (w >> 1) * 64;
  // staging decode: lane covers 16B of row (w*16 + sr), col byte sc
  const int sr = lane >> 2, sc = (lane & 3) * 16;
  const char* xbp = (const char*)xb;
  const char* wtp = (const char*)Wt;
  const char* pbp = (const char*)Pb;
  const long aOff0 = (m0 + (long)w * 16 + sr) * 2048 + sc;
  const long aOff1 = aOff0 + 4 * 16 * 2048;
  const long bOff0 = ((long)n0 + w * 16 + sr) * 2048 + sc;
  const long bOff1 = bOff0 + 4 * 16 * 2048;
  const long pOff  = ((long)w * 16 + sr) * 2048 + sc;   // used only by w<2
  const int d0 = w * 1024 + lane * 16;

  f32x4 acc[4][4] = {};
  f32x4 acc2[2][2] = {};

  // prologue: stage chunk 0 into buffer 0
  gll16(xbp + aOff0, smem + d0);
  gll16(xbp + aOff1, smem + d0 + 4096);
  gll16(wtp + bOff0, smem + 16384 + d0);
  gll16(wtp + bOff1, smem + 16384 + d0 + 4096);
  if (w < 2) gll16(pbp + pOff, smem + 32768 + d0);
  __syncthreads();

  int cur = 0;
  for (int kc = 0; kc < 32; kc++) {
    if (kc < 31) {                       // prefetch next chunk into cur^1
      const long ko = (long)(kc + 1) * 64;
      const int s = cur ^ 1;
      gll16(xbp + aOff0 + ko, smem + s * 8192 + d0);
      gll16(xbp + aOff1 + ko, smem + s * 8192 + d0 + 4096);
      gll16(wtp + bOff0 + ko, smem + 16384 + s * 8192 + d0);
      gll16(wtp + bOff1 + ko, smem + 16384 + s * 8192 + d0 + 4096);
      if (w < 2) gll16(pbp + pOff + ko, smem + 32768 + s * 2048 + d0);
    }
    const u16* At = (const u16*)(smem + cur * 8192);
    const u16* Bt = (const u16*)(smem + 16384 + cur * 8192);
    const u16* Pt = (const u16*)(smem + 32768 + cur * 2048);
    bf16x8 af[4], bq[4], af2[2], bp[2];
#pragma unroll
    for (int tm = 0; tm < 4; tm++)
      af[tm] = *(const bf16x8*)(At + (mw + tm * 16 + lrow) * 32 + quad * 8);
#pragma unroll
    for (int tn = 0; tn < 4; tn++)
      bq[tn] = *(const bf16x8*)(Bt + (nw + tn * 16 + lrow) * 32 + quad * 8);
#pragma unroll
    for (int t2 = 0; t2 < 2; t2++)
      af2[t2] = *(const bf16x8*)(At + (w * 32 + t2 * 16 + lrow) * 32 + quad * 8);
#pragma unroll
    for (int tn2 = 0; tn2 < 2; tn2++)
      bp[tn2] = *(const bf16x8*)(Pt + (tn2 * 16 + lrow) * 32 + quad * 8);
#pragma unroll
    for (int tm = 0; tm < 4; tm++)
#pragma unroll
      for (int tn = 0; tn < 4; tn++)
        acc[tm][tn] = __builtin_amdgcn_mfma_f32_16x16x32_bf16(af[tm], bq[tn], acc[tm][tn], 0, 0, 0);
#pragma unroll
    for (int t2 = 0; t2 < 2; t2++)
#pragma unroll
      for (int tn2 = 0; tn2 < 2; tn2++)
        acc2[t2][tn2] = __builtin_amdgcn_mfma_f32_16x16x32_bf16(af2[t2], bp[tn2], acc2[t2][tn2], 0, 0, 0);
    __syncthreads();   // drains prefetch vmcnt + publishes buffer cur^1
    cur ^= 1;
  }

  // stage RwT[n0..n0+128)[32] into B0 region (completes by next barrier)
  {
    const char* rwp = (const char*)RwT;
    const long rOff = ((long)n0 + w * 16 + sr) * 64 + sc;
    gll16(rwp + rOff, smem + 16384 + d0);
    gll16(rwp + rOff + 64 * 64, smem + 16384 + d0 + 4096);
  }
  // proj C-frags -> projF [128][32] fp32 (overlays A0+A1; safe: last reads
  // of A buffers completed before the loop's final barrier)
  float* projF = (float*)smem;
#pragma unroll
  for (int t2 = 0; t2 < 2; t2++)
#pragma unroll
    for (int tn2 = 0; tn2 < 2; tn2++)
#pragma unroll
      for (int r = 0; r < 4; r++)
        projF[(w * 32 + t2 * 16 + quad * 4 + r) * 32 + tn2 * 16 + lrow] = acc2[t2][tn2][r];
  __syncthreads();
  // per-token 32 coefficients -> wLds (overlays B1)
  if (tid < 128) {
    float pr[32];
#pragma unroll
    for (int j = 0; j < 32; j++) pr[j] = projF[tid * 32 + j];
    float wo[32];
#pragma unroll
    for (int k = 0; k < 8; k++) { wo[k] = gl[k] * pr[8 + k]; wo[8 + k] = -gl[k] * pr[k]; }
#pragma unroll
    for (int kp = 0; kp < 8; kp++) {
      float sv = pr[16 + kp], tv = pr[24 + kp];
#pragma unroll
      for (int k = 0; k < 8; k++) {
        float gpb = gl[k] * pr[8 + k], gpa = gl[k] * pr[k];
        sv += gpb * Ml[k * 8 + kp]       - gpa * Ml[64 + k * 8 + kp];
        tv += gpb * Ml[128 + k * 8 + kp] - gpa * Ml[192 + k * 8 + kp];
      }
      wo[16 + kp] = gl[8 + kp] * sv;
      wo[24 + kp] = gl[16 + kp] * tv;
    }
    u16* wLds = (u16*)(smem + 24576);
#pragma unroll
    for (int j = 0; j < 32; j++) wLds[tid * 32 + j] = f2bf(wo[j]);
  }
  __syncthreads();
  // final K-chunk: coeffs @ RwT
  {
    const u16* wL = (const u16*)(smem + 24576);
    const u16* Rt = (const u16*)(smem + 16384);
    bf16x8 af[4], bq[4];
#pragma unroll
    for (int tm = 0; tm < 4; tm++)
      af[tm] = *(const bf16x8*)(wL + (mw + tm * 16 + lrow) * 32 + quad * 8);
#pragma unroll
    for (int tn = 0; tn < 4; tn++)
      bq[tn] = *(const bf16x8*)(Rt + (nw + tn * 16 + lrow) * 32 + quad * 8);
#pragma unroll
    for (int tm = 0; tm < 4; tm++)
#pragma unroll
      for (int tn = 0; tn < 4; tn++)
        acc[tm][tn] = __builtin_amdgcn_mfma_f32_16x16x32_bf16(af[tm], bq[tn], acc[tm][tn], 0, 0, 0);
  }
  // epilogue: + bias, fp32 store
#pragma unroll
  for (int tn = 0; tn < 4; tn++) {
    const int col = n0 + nw + tn * 16 + lrow;
    const float bias = bb[col];
#pragma unroll
    for (int tm = 0; tm < 4; tm++)
#pragma unroll
      for (int r = 0; r < 4; r++) {
        long row = m0 + mw + tm * 16 + quad * 4 + r;
        out[row * DD + col] = acc[tm][tn][r] + bias;
      }
  }
}

// ---------------------------------------------------------------------------
// mode-B fallback GEMM (old register-staged path, fp32 x with convert)
// ---------------------------------------------------------------------------
template <bool XB>
__global__ __launch_bounds__(256) void k3_fused(
    const float* __restrict__ xf, const u16* __restrict__ xb,
    const u16* __restrict__ Wt, const u16* __restrict__ Pb,
    const float* __restrict__ gates, const float* __restrict__ Mbuf,
    const u16* __restrict__ RwT, const float* __restrict__ bb,
    float* __restrict__ out) {
  __shared__ __align__(16) u16 At[4096];
  __shared__ __align__(16) u16 Bt[4096];
  __shared__ __align__(16) u16 Pt[1024];
  __shared__ float projF[128 * 32];
  __shared__ __align__(16) u16 wLds[4096];
  __shared__ float Ml[256];
  __shared__ float gl[24];
  const int tid = threadIdx.x, lane = tid & 63, w = tid >> 6;
  const int quad = lane >> 4, lrow = lane & 15;
  const int bn = blockIdx.x & 7, bm = blockIdx.x >> 3;
  const long m0 = (long)bm * 128;
  const int n0 = bn * 128;
  const int batch = bm >> 5;
  Ml[tid] = Mbuf[tid];
  if (tid < 24) gl[tid] = gates[batch * 32 + tid];
  const int mw = (w & 1) * 64, nw = (w >> 1) * 64;
  const int p0 = (w * 2) * 1024 + lane * 16, p1 = p0 + 1024;
  f32x4 acc[4][4] = {};
  f32x4 acc2[2][2] = {};
  for (int kc = 0; kc < 32; kc++) {
    uint4 vb0 = *(const uint4*)((const char*)Wt + (long)(n0 + (p0 >> 6)) * 2048 + kc * 64 + (p0 & 63));
    uint4 vb1 = *(const uint4*)((const char*)Wt + (long)(n0 + (p1 >> 6)) * 2048 + kc * 64 + (p1 & 63));
    uint4 vp;
    if (tid < 128)
      vp = *(const uint4*)((const char*)Pb + (tid >> 2) * 2048 + kc * 64 + (tid & 3) * 16);
    if (XB) {
      uint4 va0 = *(const uint4*)((const char*)xb + (m0 + (p0 >> 6)) * 2048 + kc * 64 + (p0 & 63));
      uint4 va1 = *(const uint4*)((const char*)xb + (m0 + (p1 >> 6)) * 2048 + kc * 64 + (p1 & 63));
      *(uint4*)((char*)At + p0) = va0;
      *(uint4*)((char*)At + p1) = va1;
    } else {
      ushort4 oa[4];
#pragma unroll
      for (int i = 0; i < 4; i++) {
        int fi = i * 256 + tid, row = fi >> 3, c4 = (fi & 7) * 4;
        float4 v = *(const float4*)(xf + (m0 + row) * DD + kc * 32 + c4);
        oa[i].x = f2bf(v.x); oa[i].y = f2bf(v.y); oa[i].z = f2bf(v.z); oa[i].w = f2bf(v.w);
      }
#pragma unroll
      for (int i = 0; i < 4; i++) {
        int fi = i * 256 + tid, row = fi >> 3, c4 = (fi & 7) * 4;
        *(ushort4*)(At + row * 32 + c4) = oa[i];
      }
    }
    *(uint4*)((char*)Bt + p0) = vb0;
    *(uint4*)((char*)Bt + p1) = vb1;
    if (tid < 128) *(uint4*)((char*)Pt + (tid >> 2) * 64 + (tid & 3) * 16) = vp;
    __syncthreads();
    bf16x8 af[4], bq[4], af2[2], bp[2];
#pragma unroll
    for (int tm = 0; tm < 4; tm++)
      af[tm] = *(const bf16x8*)(At + (mw + tm * 16 + lrow) * 32 + quad * 8);
#pragma unroll
    for (int tn = 0; tn < 4; tn++)
      bq[tn] = *(const bf16x8*)(Bt + (nw + tn * 16 + lrow) * 32 + quad * 8);
#pragma unroll
    for (int t2 = 0; t2 < 2; t2++)
      af2[t2] = *(const bf16x8*)(At + (w * 32 + t2 * 16 + lrow) * 32 + quad * 8);
#pragma unroll
    for (int tn2 = 0; tn2 < 2; tn2++)
      bp[tn2] = *(const bf16x8*)(Pt + (tn2 * 16 + lrow) * 32 + quad * 8);
#pragma unroll
    for (int tm = 0; tm < 4; tm++)
#pragma unroll
      for (int tn = 0; tn < 4; tn++)
        acc[tm][tn] = __builtin_amdgcn_mfma_f32_16x16x32_bf16(af[tm], bq[tn], acc[tm][tn], 0, 0, 0);
#pragma unroll
    for (int t2 = 0; t2 < 2; t2++)
#pragma unroll
      for (int tn2 = 0; tn2 < 2; tn2++)
        acc2[t2][tn2] = __builtin_amdgcn_mfma_f32_16x16x32_bf16(af2[t2], bp[tn2], acc2[t2][tn2], 0, 0, 0);
    __syncthreads();
  }
#pragma unroll
  for (int t2 = 0; t2 < 2; t2++)
#pragma unroll
    for (int tn2 = 0; tn2 < 2; tn2++)
#pragma unroll
      for (int r = 0; r < 4; r++)
        projF[(w * 32 + t2 * 16 + quad * 4 + r) * 32 + tn2 * 16 + lrow] = acc2[t2][tn2][r];
  {
    uint4 vr0 = *(const uint4*)((const char*)RwT + (long)(n0 + (p0 >> 6)) * 64 + (p0 & 63));
    uint4 vr1 = *(const uint4*)((const char*)RwT + (long)(n0 + (p1 >> 6)) * 64 + (p1 & 63));
    *(uint4*)((char*)Bt + p0) = vr0;
    *(uint4*)((char*)Bt + p1) = vr1;
  }
  __syncthreads();
  if (tid < 128) {
    float pr[32];
#pragma unroll
    for (int j = 0; j < 32; j++) pr[j] = projF[tid * 32 + j];
    float wo[32];
#pragma unroll
    for (int k = 0; k < 8; k++) { wo[k] = gl[k] * pr[8 + k]; wo[8 + k] = -gl[k] * pr[k]; }
#pragma unroll
    for (int kp = 0; kp < 8; kp++) {
      float sv = pr[16 + kp], tv = pr[24 + kp];
#pragma unroll
      for (int k = 0; k < 8; k++) {
        float gpb = gl[k] * pr[8 + k], gpa = gl[k] * pr[k];
        sv += gpb * Ml[k * 8 + kp]       - gpa * Ml[64 + k * 8 + kp];
        tv += gpb * Ml[128 + k * 8 + kp] - gpa * Ml[192 + k * 8 + kp];
      }
      wo[16 + kp] = gl[8 + kp] * sv;
      wo[24 + kp] = gl[16 + kp] * tv;
    }
#pragma unroll
    for (int j = 0; j < 32; j++) wLds[tid * 32 + j] = f2bf(wo[j]);
  }
  __syncthreads();
  {
    bf16x8 af[4], bq[4];
#pragma unroll
    for (int tm = 0; tm < 4; tm++)
      af[tm] = *(const bf16x8*)(wLds + (mw + tm * 16 + lrow) * 32 + quad * 8);
#pragma unroll
    for (int tn = 0; tn < 4; tn++)
      bq[tn] = *(const bf16x8*)(Bt + (nw + tn * 16 + lrow) * 32 + quad * 8);
#pragma unroll
    for (int tm = 0; tm < 4; tm++)
#pragma unroll
      for (int tn = 0; tn < 4; tn++)
        acc[tm][tn] = __builtin_amdgcn_mfma_f32_16x16x32_bf16(af[tm], bq[tn], acc[tm][tn], 0, 0, 0);
  }
#pragma unroll
  for (int tn = 0; tn < 4; tn++) {
    const int col = n0 + nw + tn * 16 + lrow;
    const float bias = bb[col];
#pragma unroll
    for (int tm = 0; tm < 4; tm++)
#pragma unroll
      for (int r = 0; r < 4; r++) {
        long row = m0 + mw + tm * 16 + quad * 4 + r;
        out[row * DD + col] = acc[tm][tn][r] + bias;
      }
  }
}

// ---------------------------------------------------------------------------
extern "C" void kernel_launch(void* const* d_in, const int* in_sizes, int n_in,
                              void* d_out, int out_size, void* d_ws, size_t ws_size,
                              hipStream_t stream) {
  const float* x   = (const float*)d_in[0];
  const float* Wb  = (const float*)d_in[1];
  const float* bb  = (const float*)d_in[2];
  const float* lng = (const float*)d_in[3];
  const float* lnb = (const float*)d_in[4];
  const float* Wc1 = (const float*)d_in[5];
  const float* bc1 = (const float*)d_in[6];
  const float* Wc2 = (const float*)d_in[7];
  const float* bc2 = (const float*)d_in[8];
  const float* Wrg = (const float*)d_in[9];
  const float* brg = (const float*)d_in[10];
  const float* Wrc = (const float*)d_in[11];
  const float* brc = (const float*)d_in[12];
  const float* Wsg = (const float*)d_in[13];
  const float* bsg = (const float*)d_in[14];
  const float* Wlc = (const float*)d_in[15];
  const float* blc = (const float*)d_in[16];
  const float* Us  = (const float*)d_in[17];
  const float* Vs  = (const float*)d_in[18];
  const float* Ul  = (const float*)d_in[19];
  const float* Vl  = (const float*)d_in[20];
  const float* Ao  = (const float*)d_in[21];
  const float* Bo  = (const float*)d_in[22];

  char* ws = (char*)d_ws;
  float* pooled = (float*)(ws + 0);         //  4*1024 f32  [memset]
  float* AWBW   = (float*)(ws + 16384);     // 16*1024 f32  [memset]
  float* h1pre  = (float*)(ws + 81920);     //  4*128 f32   [memset] -> 83968
  float* gates  = (float*)(ws + 83968);     //  4*32  f32   -> 84480
  float* Mbuf   = (float*)(ws + 84480);     //  256   f32   -> 85504
  u16*   RwT    = (u16*)  (ws + 85504);     // 1024*32 bf16 -> 151040
  u16*   Pb     = (u16*)  (ws + 151040);    // 32*1024 bf16 -> 216576
  u16*   Wt     = (u16*)  (ws + 216576);    // 1024*1024 bf16 (2 MB) -> 2313728
  u16*   xb     = (u16*)  (ws + 2313728);   // 16384*1024 bf16 (32 MB), mode A
  float* out    = (float*)d_out;

  const bool modeA = ws_size >= (size_t)2313728 + 33554432;

  (void)hipMemsetAsync(d_ws, 0, 83968, stream);   // pooled + AWBW + h1pre
  if (modeA)
    k01_pre<true><<<552, 256, 0, stream>>>(x, xb, pooled, Wb, Ao, Bo, Us, Ul,
                                           AWBW, Mbuf, Pb, Wt);
  else
    k01_pre<false><<<552, 256, 0, stream>>>(x, xb, pooled, Wb, Ao, Bo, Us, Ul,
                                            AWBW, Mbuf, Pb, Wt);
  k2a_h1<<<32, 256, 0, stream>>>(pooled, lng, lnb, Wc1, h1pre);
  k2b_gates_pack<<<8, 256, 0, stream>>>(h1pre, AWBW, Vs, Vl,
                                        bc1, Wc2, bc2, Wrg, brg, Wrc, brc,
                                        Wsg, bsg, Wlc, blc, gates, RwT);
  if (modeA)
    k3a_fused<<<1024, 256, 0, stream>>>(xb, Wt, Pb, gates, Mbuf, RwT, bb, out);
  else
    k3_fused<false><<<1024, 256, 0, stream>>>(x, xb, Wt, Pb, gates, Mbuf, RwT, bb, out);
}

// Round 3
// 298.675 us; speedup vs baseline: 1.1972x; 1.0401x over previous
//
#include <hip/hip_runtime.h>

typedef unsigned short u16;
typedef unsigned int   u32;
typedef __bf16 bf16x8 __attribute__((ext_vector_type(8)));
typedef float  f32x4  __attribute__((ext_vector_type(4)));

#define DD 1024

__device__ __forceinline__ u16 f2bf(float f) {
  u32 u = __float_as_uint(f);
  u32 r = (u + 0x7FFFu + ((u >> 16) & 1u)) >> 16;
  return (u16)r;
}

// async global->LDS, 16B per lane. Dest must be wave-uniform-base + lane*16.
typedef const __attribute__((address_space(1))) void* gp1;
typedef __attribute__((address_space(3))) void* lp3;
__device__ __forceinline__ void gll16(const void* g, void* l) {
  __builtin_amdgcn_global_load_lds((gp1)g, (lp3)l, 16, 0, 0);
}

// ---------------------------------------------------------------------------
// k01: merged pre-kernel (independent work -> run concurrently).
// blocks 0..255   : x fp32 -> bf16 convert (XB) + pooled column sums
// blocks 256..287 : AWBW[16][1024] = {A,B}@W_base (fp32 atomics, split-i)
// blocks 288..291 : Mbuf: 4 Gram 8x8 (A.Us, B.Us, A.Ul, B.Ul)
// blocks 292..295 : Pb[32][1024] = bf16([Ao;Bo;Us;Ul])
// blocks 296..551 : Wt[n][k] = bf16(W[k][n])  (transpose + convert)
// ---------------------------------------------------------------------------
template <bool XB>
__global__ __launch_bounds__(256) void k01_pre(
    const float* __restrict__ x, u16* __restrict__ xb, float* __restrict__ pooled,
    const float* __restrict__ W,
    const float* __restrict__ Ao, const float* __restrict__ Bo,
    const float* __restrict__ Us, const float* __restrict__ Ul,
    float* __restrict__ AWBW, float* __restrict__ Mbuf,
    u16* __restrict__ Pb, u16* __restrict__ Wt) {
  const int tid = threadIdx.x;
  int bid = blockIdx.x;
  if (bid < 256) {
    const int b = bid >> 6;
    const long r0 = (long)bid * 64;
    const int c0 = tid * 4;
    float s0 = 0.f, s1 = 0.f, s2 = 0.f, s3 = 0.f;
    for (int r = 0; r < 64; r++) {
      float4 v = *(const float4*)(x + (r0 + r) * DD + c0);
      if (XB) {
        ushort4 o;
        o.x = f2bf(v.x); o.y = f2bf(v.y); o.z = f2bf(v.z); o.w = f2bf(v.w);
        *(ushort4*)(xb + (r0 + r) * DD + c0) = o;
      }
      s0 += v.x; s1 += v.y; s2 += v.z; s3 += v.w;
    }
    atomicAdd(&pooled[b * DD + c0 + 0], s0);
    atomicAdd(&pooled[b * DD + c0 + 1], s1);
    atomicAdd(&pooled[b * DD + c0 + 2], s2);
    atomicAdd(&pooled[b * DD + c0 + 3], s3);
    return;
  }
  bid -= 256;
  if (bid < 32) {
    __shared__ float red2[2][128][16];
    const int m = bid;
    const int n = (m & 7) * 128 + (tid & 127), q = m >> 3, ih = tid >> 7;
    float acc[16];
#pragma unroll
    for (int k = 0; k < 16; k++) acc[k] = 0.f;
    const int ib = q * 256 + ih * 128;
    for (int i = ib; i < ib + 128; i++) {
      float wv = W[(long)i * DD + n];
#pragma unroll
      for (int k = 0; k < 8; k++) {
        acc[k]     += Ao[k * DD + i] * wv;
        acc[k + 8] += Bo[k * DD + i] * wv;
      }
    }
#pragma unroll
    for (int k = 0; k < 16; k++) red2[ih][tid & 127][k] = acc[k];
    __syncthreads();
    if (ih == 0)
#pragma unroll
      for (int k = 0; k < 16; k++)
        atomicAdd(&AWBW[k * DD + n], red2[0][tid][k] + red2[1][tid][k]);
  } else if (bid < 36) {
    __shared__ float red[64][4];
    const int m = bid - 32;
    const float* L  = (m == 0 || m == 2) ? Ao : Bo;
    const float* Rr = (m < 2) ? Us : Ul;
    const int o = tid >> 2, ch = tid & 3;
    const int k = o >> 3, kp = o & 7;
    float a = 0.f;
    for (int i = ch * 256; i < ch * 256 + 256; i++)
      a += L[(long)k * DD + i] * Rr[(long)kp * DD + i];
    red[o][ch] = a;
    __syncthreads();
    if (tid < 64) Mbuf[m * 64 + tid] = red[tid][0] + red[tid][1] + red[tid][2] + red[tid][3];
  } else if (bid < 40) {
    const int m = bid - 36;
    const float* src = m == 0 ? Ao : m == 1 ? Bo : m == 2 ? Us : Ul;
#pragma unroll
    for (int j = 0; j < 8; j++)
      for (int q = 0; q < 4; q++) {
        int i = q * 256 + tid;
        Pb[(m * 8 + j) * DD + i] = f2bf(src[j * DD + i]);
      }
  } else {
    __shared__ u16 T[64][66];
    const int t = bid - 40, tr = t >> 4, tc = t & 15;
#pragma unroll
    for (int q2 = 0; q2 < 16; q2++) {
      int idx = q2 * 256 + tid, r = idx >> 6, c = idx & 63;
      T[r][c] = f2bf(W[(long)(tr * 64 + r) * DD + tc * 64 + c]);
    }
    __syncthreads();
#pragma unroll
    for (int q2 = 0; q2 < 16; q2++) {
      int idx = q2 * 256 + tid, c = idx >> 6, r = idx & 63;
      Wt[(long)(tc * 64 + c) * DD + tr * 64 + r] = T[r][c];
    }
  }
}

// ---------------------------------------------------------------------------
// k2ab: merged conditioner chain (saves one launch).
// blocks 0..31 : h1pre[b][j] partials (z@Wc1 chunk), then signal counter.
// blocks 32..35: spin until counter==32, then gates[b][24] for b=bid-32.
// blocks 36..39: pack RwT[n][32] = bf16{AW(8) BW(8) Vs(8) Vl(8)}(., n).
// 40 blocks << 256 CUs -> all co-resident -> spin is deadlock-free.
// Cross-block h1pre passed via atomics (coherent across XCDs).
// ---------------------------------------------------------------------------
__global__ __launch_bounds__(256) void k2ab(
    const float* __restrict__ pooledsum,
    const float* __restrict__ lng, const float* __restrict__ lnb,
    const float* __restrict__ Wc1, float* __restrict__ h1pre,
    const float* __restrict__ AWBW, const float* Vs, const float* Vl,
    const float* bc1, const float* Wc2, const float* bc2,
    const float* Wrg, const float* brg, const float* Wrc, const float* brc,
    const float* Wsg, const float* bsg, const float* Wlc, const float* blc,
    float* __restrict__ gates, u16* __restrict__ RwT,
    u32* __restrict__ cnt) {
  const int tid = threadIdx.x;
  if (blockIdx.x < 32) {
    // ---- k2a body: LN + z@Wc1 chunk partial ----
    __shared__ float zs[1024];
    __shared__ float wsh[16384];
    __shared__ float red[256];
    const int b = blockIdx.x >> 3, ch = blockIdx.x & 7;
    float4 v = *(const float4*)(pooledsum + b * DD + tid * 4);
    v.x *= (1.f / 4096.f); v.y *= (1.f / 4096.f); v.z *= (1.f / 4096.f); v.w *= (1.f / 4096.f);
    float s = v.x + v.y + v.z + v.w;
    float sq = v.x * v.x + v.y * v.y + v.z * v.z + v.w * v.w;
    red[tid] = s; __syncthreads();
    for (int st = 128; st > 0; st >>= 1) { if (tid < st) red[tid] += red[tid + st]; __syncthreads(); }
    float mu = red[0] * (1.f / 1024.f);
    __syncthreads();
    red[tid] = sq; __syncthreads();
    for (int st = 128; st > 0; st >>= 1) { if (tid < st) red[tid] += red[tid + st]; __syncthreads(); }
    float var = red[0] * (1.f / 1024.f) - mu * mu;
    float rs = rsqrtf(var + 1e-5f);
    __syncthreads();
    {
      float4 g = *(const float4*)(lng + tid * 4);
      float4 be = *(const float4*)(lnb + tid * 4);
      zs[tid * 4 + 0] = (v.x - mu) * rs * g.x + be.x;
      zs[tid * 4 + 1] = (v.y - mu) * rs * g.y + be.y;
      zs[tid * 4 + 2] = (v.z - mu) * rs * g.z + be.z;
      zs[tid * 4 + 3] = (v.w - mu) * rs * g.w + be.w;
    }
    {
      const float4* src = (const float4*)(Wc1 + ch * 16384);
      float4* dst = (float4*)wsh;
#pragma unroll
      for (int it = 0; it < 16; it++) dst[it * 256 + tid] = src[it * 256 + tid];
    }
    __syncthreads();
    const int j = tid & 127, half = tid >> 7;
    float a = 0.f;
#pragma unroll 8
    for (int dd = 0; dd < 64; dd++) {
      int ldi = half * 64 + dd;
      a += zs[ch * 128 + ldi] * wsh[ldi * 128 + j];
    }
    red[tid] = a;
    __syncthreads();
    if (tid < 128) atomicAdd(&h1pre[b * 128 + tid], red[tid] + red[tid + 128]);
    __syncthreads();                 // drain this block's h1pre atomics
    if (tid == 0) atomicAdd(cnt, 1u);  // then signal (device-scope)
  } else if (blockIdx.x < 36) {
    // ---- gate block for batch b ----
    __shared__ float wc2sh[16384];
    __shared__ float h1s[128], hb[128];
    __shared__ float red[256];
    __shared__ float hw[3200];
    const int b = (int)blockIdx.x - 32;
    // stage weights FIRST (independent of h1pre) to hide the spin
    {
      const float4* src = (const float4*)Wc2;
      float4* dst = (float4*)wc2sh;
#pragma unroll
      for (int it = 0; it < 16; it++) dst[it * 256 + tid] = src[it * 256 + tid];
    }
    for (int idx = tid; idx < 3200; idx += 256) {
      float vv;
      if (idx < 128)       vv = Wrg[idx];
      else if (idx < 1152) vv = Wrc[idx - 128];
      else if (idx < 2176) vv = Wsg[idx - 1152];
      else                 vv = Wlc[idx - 2176];
      hw[idx] = vv;
    }
    if (tid == 0) {
      while (atomicAdd(cnt, 0u) < 32u) __builtin_amdgcn_s_sleep(8);
    }
    __syncthreads();
    if (tid < 128) {
      float hv = atomicAdd(&h1pre[b * 128 + tid], 0.f) + bc1[tid];  // coherent read
      float th = tanhf(0.7978845608028654f * (hv + 0.044715f * hv * hv * hv));
      h1s[tid] = 0.5f * hv * (1.f + th);
    }
    __syncthreads();
    const int i = tid & 127, half = tid >> 7;
    float a = 0.f;
#pragma unroll 8
    for (int k = 0; k < 64; k++) {
      int kk = half * 64 + k;
      a += h1s[kk] * wc2sh[kk * 128 + i];
    }
    red[tid] = a;
    __syncthreads();
    if (tid < 128) hb[tid] = red[tid] + red[tid + 128] + bc2[tid];
    __syncthreads();
    if (tid < 25) {
      float acc;
      if (tid == 0) {
        acc = brg[0];
        for (int k = 0; k < 128; k++) acc += hb[k] * hw[k];
        red[0] = 1.f / (1.f + expf(-acc));
      } else if (tid < 9) {
        int ci = tid - 1; acc = brc[ci];
        for (int k = 0; k < 128; k++) acc += hb[k] * hw[128 + k * 8 + ci];
        red[tid] = tanhf(acc);
      } else if (tid < 17) {
        int ci = tid - 9; acc = bsg[ci];
        for (int k = 0; k < 128; k++) acc += hb[k] * hw[1152 + k * 8 + ci];
        red[tid] = tanhf(acc);
      } else {
        int ci = tid - 17; acc = blc[ci];
        for (int k = 0; k < 128; k++) acc += hb[k] * hw[2176 + k * 8 + ci];
        red[tid] = tanhf(acc);
      }
    }
    __syncthreads();
    if (tid < 24) {
      float g = red[0];
      gates[b * 32 + tid] = (tid < 8) ? g * red[1 + tid] : red[1 + tid];
    }
  } else {
    const int n = (int)(blockIdx.x - 36) * 256 + tid;
#pragma unroll
    for (int j = 0; j < 8; j++) {
      RwT[n * 32 + j]      = f2bf(AWBW[j * DD + n]);
      RwT[n * 32 + 8 + j]  = f2bf(AWBW[(8 + j) * DD + n]);
      RwT[n * 32 + 16 + j] = f2bf(Vs[(long)j * DD + n]);
      RwT[n * 32 + 24 + j] = f2bf(Vl[(long)j * DD + n]);
    }
  }
}

// ---------------------------------------------------------------------------
// k3a (mode A): fused GEMM, double-buffered LDS via global_load_lds (16B),
// ONE barrier per K-chunk.  XCD-bijective swizzle: all 8 bn-blocks of a bm
// land on the same XCD (dispatch round-robin blk%8 -> XCD), so the A-slab is
// fetched from HBM once per XCD and the 8 readers hit L2; Wt (2 MB) stays
// L2-resident per XCD.  LDS map (bytes): A0 0..8K, A1 8..16K, B0 16..24K,
// B1 24..32K, P0/P1 32768/34816, Ml 36864, gl 37888.
// ---------------------------------------------------------------------------
__global__ __launch_bounds__(256, 3) void k3a_fused(
    const u16* __restrict__ xb, const u16* __restrict__ Wt,
    const u16* __restrict__ Pb, const float* __restrict__ gates,
    const float* __restrict__ Mbuf, const u16* __restrict__ RwT,
    const float* __restrict__ bb, float* __restrict__ out) {
  __shared__ __align__(16) char smem[38912];
  const int tid = threadIdx.x, lane = tid & 63, w = tid >> 6;
  const int quad = lane >> 4, lrow = lane & 15;
  // XCD swizzle: xcd = blk&7; bm = xcd*16 + blk>>6; bn = (blk>>3)&7
  const int bidx = blockIdx.x;
  const int bm = (bidx & 7) * 16 + (bidx >> 6);
  const int bn = (bidx >> 3) & 7;
  const long m0 = (long)bm * 128;
  const int n0 = bn * 128;
  const int batch = bm >> 5;
  float* Ml = (float*)(smem + 36864);
  float* gl = (float*)(smem + 37888);
  Ml[tid] = Mbuf[tid];
  if (tid < 24) gl[tid] = gates[batch * 32 + tid];
  const int mw = (w & 1) * 64, nw = (w >> 1) * 64;
  // staging decode: lane covers 16B of row (w*16 + sr), col byte sc
  const int sr = lane >> 2, sc = (lane & 3) * 16;
  const char* xbp = (const char*)xb;
  const char* wtp = (const char*)Wt;
  const char* pbp = (const char*)Pb;
  const long aOff0 = (m0 + (long)w * 16 + sr) * 2048 + sc;
  const long aOff1 = aOff0 + 4 * 16 * 2048;
  const long bOff0 = ((long)n0 + w * 16 + sr) * 2048 + sc;
  const long bOff1 = bOff0 + 4 * 16 * 2048;
  const long pOff  = ((long)w * 16 + sr) * 2048 + sc;   // used only by w<2
  const int d0 = w * 1024 + lane * 16;

  f32x4 acc[4][4] = {};
  f32x4 acc2[2][2] = {};

  // prologue: stage chunk 0 into buffer 0
  gll16(xbp + aOff0, smem + d0);
  gll16(xbp + aOff1, smem + d0 + 4096);
  gll16(wtp + bOff0, smem + 16384 + d0);
  gll16(wtp + bOff1, smem + 16384 + d0 + 4096);
  if (w < 2) gll16(pbp + pOff, smem + 32768 + d0);
  __syncthreads();

  int cur = 0;
  for (int kc = 0; kc < 32; kc++) {
    if (kc < 31) {                       // prefetch next chunk into cur^1
      const long ko = (long)(kc + 1) * 64;
      const int s = cur ^ 1;
      gll16(xbp + aOff0 + ko, smem + s * 8192 + d0);
      gll16(xbp + aOff1 + ko, smem + s * 8192 + d0 + 4096);
      gll16(wtp + bOff0 + ko, smem + 16384 + s * 8192 + d0);
      gll16(wtp + bOff1 + ko, smem + 16384 + s * 8192 + d0 + 4096);
      if (w < 2) gll16(pbp + pOff + ko, smem + 32768 + s * 2048 + d0);
    }
    const u16* At = (const u16*)(smem + cur * 8192);
    const u16* Bt = (const u16*)(smem + 16384 + cur * 8192);
    const u16* Pt = (const u16*)(smem + 32768 + cur * 2048);
    bf16x8 af[4], bq[4], af2[2], bp[2];
#pragma unroll
    for (int tm = 0; tm < 4; tm++)
      af[tm] = *(const bf16x8*)(At + (mw + tm * 16 + lrow) * 32 + quad * 8);
#pragma unroll
    for (int tn = 0; tn < 4; tn++)
      bq[tn] = *(const bf16x8*)(Bt + (nw + tn * 16 + lrow) * 32 + quad * 8);
#pragma unroll
    for (int t2 = 0; t2 < 2; t2++)
      af2[t2] = *(const bf16x8*)(At + (w * 32 + t2 * 16 + lrow) * 32 + quad * 8);
#pragma unroll
    for (int tn2 = 0; tn2 < 2; tn2++)
      bp[tn2] = *(const bf16x8*)(Pt + (tn2 * 16 + lrow) * 32 + quad * 8);
#pragma unroll
    for (int tm = 0; tm < 4; tm++)
#pragma unroll
      for (int tn = 0; tn < 4; tn++)
        acc[tm][tn] = __builtin_amdgcn_mfma_f32_16x16x32_bf16(af[tm], bq[tn], acc[tm][tn], 0, 0, 0);
#pragma unroll
    for (int t2 = 0; t2 < 2; t2++)
#pragma unroll
      for (int tn2 = 0; tn2 < 2; tn2++)
        acc2[t2][tn2] = __builtin_amdgcn_mfma_f32_16x16x32_bf16(af2[t2], bp[tn2], acc2[t2][tn2], 0, 0, 0);
    __syncthreads();   // drains prefetch vmcnt + publishes buffer cur^1
    cur ^= 1;
  }

  // stage RwT[n0..n0+128)[32] into B0 region (completes by next barrier)
  {
    const char* rwp = (const char*)RwT;
    const long rOff = ((long)n0 + w * 16 + sr) * 64 + sc;
    gll16(rwp + rOff, smem + 16384 + d0);
    gll16(rwp + rOff + 64 * 64, smem + 16384 + d0 + 4096);
  }
  // proj C-frags -> projF [128][32] fp32 (overlays A0+A1)
  float* projF = (float*)smem;
#pragma unroll
  for (int t2 = 0; t2 < 2; t2++)
#pragma unroll
    for (int tn2 = 0; tn2 < 2; tn2++)
#pragma unroll
      for (int r = 0; r < 4; r++)
        projF[(w * 32 + t2 * 16 + quad * 4 + r) * 32 + tn2 * 16 + lrow] = acc2[t2][tn2][r];
  __syncthreads();
  // per-token 32 coefficients -> wLds (overlays B1)
  if (tid < 128) {
    float pr[32];
#pragma unroll
    for (int j = 0; j < 32; j++) pr[j] = projF[tid * 32 + j];
    float wo[32];
#pragma unroll
    for (int k = 0; k < 8; k++) { wo[k] = gl[k] * pr[8 + k]; wo[8 + k] = -gl[k] * pr[k]; }
#pragma unroll
    for (int kp = 0; kp < 8; kp++) {
      float sv = pr[16 + kp], tv = pr[24 + kp];
#pragma unroll
      for (int k = 0; k < 8; k++) {
        float gpb = gl[k] * pr[8 + k], gpa = gl[k] * pr[k];
        sv += gpb * Ml[k * 8 + kp]       - gpa * Ml[64 + k * 8 + kp];
        tv += gpb * Ml[128 + k * 8 + kp] - gpa * Ml[192 + k * 8 + kp];
      }
      wo[16 + kp] = gl[8 + kp] * sv;
      wo[24 + kp] = gl[16 + kp] * tv;
    }
    u16* wLds = (u16*)(smem + 24576);
#pragma unroll
    for (int j = 0; j < 32; j++) wLds[tid * 32 + j] = f2bf(wo[j]);
  }
  __syncthreads();
  // final K-chunk: coeffs @ RwT
  {
    const u16* wL = (const u16*)(smem + 24576);
    const u16* Rt = (const u16*)(smem + 16384);
    bf16x8 af[4], bq[4];
#pragma unroll
    for (int tm = 0; tm < 4; tm++)
      af[tm] = *(const bf16x8*)(wL + (mw + tm * 16 + lrow) * 32 + quad * 8);
#pragma unroll
    for (int tn = 0; tn < 4; tn++)
      bq[tn] = *(const bf16x8*)(Rt + (nw + tn * 16 + lrow) * 32 + quad * 8);
#pragma unroll
    for (int tm = 0; tm < 4; tm++)
#pragma unroll
      for (int tn = 0; tn < 4; tn++)
        acc[tm][tn] = __builtin_amdgcn_mfma_f32_16x16x32_bf16(af[tm], bq[tn], acc[tm][tn], 0, 0, 0);
  }
  // epilogue: + bias, fp32 store
#pragma unroll
  for (int tn = 0; tn < 4; tn++) {
    const int col = n0 + nw + tn * 16 + lrow;
    const float bias = bb[col];
#pragma unroll
    for (int tm = 0; tm < 4; tm++)
#pragma unroll
      for (int r = 0; r < 4; r++) {
        long row = m0 + mw + tm * 16 + quad * 4 + r;
        out[row * DD + col] = acc[tm][tn][r] + bias;
      }
  }
}

// ---------------------------------------------------------------------------
// mode-B fallback GEMM (register-staged path, fp32 x with convert)
// ---------------------------------------------------------------------------
template <bool XB>
__global__ __launch_bounds__(256) void k3_fused(
    const float* __restrict__ xf, const u16* __restrict__ xb,
    const u16* __restrict__ Wt, const u16* __restrict__ Pb,
    const float* __restrict__ gates, const float* __restrict__ Mbuf,
    const u16* __restrict__ RwT, const float* __restrict__ bb,
    float* __restrict__ out) {
  __shared__ __align__(16) u16 At[4096];
  __shared__ __align__(16) u16 Bt[4096];
  __shared__ __align__(16) u16 Pt[1024];
  __shared__ float projF[128 * 32];
  __shared__ __align__(16) u16 wLds[4096];
  __shared__ float Ml[256];
  __shared__ float gl[24];
  const int tid = threadIdx.x, lane = tid & 63, w = tid >> 6;
  const int quad = lane >> 4, lrow = lane & 15;
  const int bn = blockIdx.x & 7, bm = blockIdx.x >> 3;
  const long m0 = (long)bm * 128;
  const int n0 = bn * 128;
  const int batch = bm >> 5;
  Ml[tid] = Mbuf[tid];
  if (tid < 24) gl[tid] = gates[batch * 32 + tid];
  const int mw = (w & 1) * 64, nw = (w >> 1) * 64;
  const int p0 = (w * 2) * 1024 + lane * 16, p1 = p0 + 1024;
  f32x4 acc[4][4] = {};
  f32x4 acc2[2][2] = {};
  for (int kc = 0; kc < 32; kc++) {
    uint4 vb0 = *(const uint4*)((const char*)Wt + (long)(n0 + (p0 >> 6)) * 2048 + kc * 64 + (p0 & 63));
    uint4 vb1 = *(const uint4*)((const char*)Wt + (long)(n0 + (p1 >> 6)) * 2048 + kc * 64 + (p1 & 63));
    uint4 vp;
    if (tid < 128)
      vp = *(const uint4*)((const char*)Pb + (tid >> 2) * 2048 + kc * 64 + (tid & 3) * 16);
    if (XB) {
      uint4 va0 = *(const uint4*)((const char*)xb + (m0 + (p0 >> 6)) * 2048 + kc * 64 + (p0 & 63));
      uint4 va1 = *(const uint4*)((const char*)xb + (m0 + (p1 >> 6)) * 2048 + kc * 64 + (p1 & 63));
      *(uint4*)((char*)At + p0) = va0;
      *(uint4*)((char*)At + p1) = va1;
    } else {
      ushort4 oa[4];
#pragma unroll
      for (int i = 0; i < 4; i++) {
        int fi = i * 256 + tid, row = fi >> 3, c4 = (fi & 7) * 4;
        float4 v = *(const float4*)(xf + (m0 + row) * DD + kc * 32 + c4);
        oa[i].x = f2bf(v.x); oa[i].y = f2bf(v.y); oa[i].z = f2bf(v.z); oa[i].w = f2bf(v.w);
      }
#pragma unroll
      for (int i = 0; i < 4; i++) {
        int fi = i * 256 + tid, row = fi >> 3, c4 = (fi & 7) * 4;
        *(ushort4*)(At + row * 32 + c4) = oa[i];
      }
    }
    *(uint4*)((char*)Bt + p0) = vb0;
    *(uint4*)((char*)Bt + p1) = vb1;
    if (tid < 128) *(uint4*)((char*)Pt + (tid >> 2) * 64 + (tid & 3) * 16) = vp;
    __syncthreads();
    bf16x8 af[4], bq[4], af2[2], bp[2];
#pragma unroll
    for (int tm = 0; tm < 4; tm++)
      af[tm] = *(const bf16x8*)(At + (mw + tm * 16 + lrow) * 32 + quad * 8);
#pragma unroll
    for (int tn = 0; tn < 4; tn++)
      bq[tn] = *(const bf16x8*)(Bt + (nw + tn * 16 + lrow) * 32 + quad * 8);
#pragma unroll
    for (int t2 = 0; t2 < 2; t2++)
      af2[t2] = *(const bf16x8*)(At + (w * 32 + t2 * 16 + lrow) * 32 + quad * 8);
#pragma unroll
    for (int tn2 = 0; tn2 < 2; tn2++)
      bp[tn2] = *(const bf16x8*)(Pt + (tn2 * 16 + lrow) * 32 + quad * 8);
#pragma unroll
    for (int tm = 0; tm < 4; tm++)
#pragma unroll
      for (int tn = 0; tn < 4; tn++)
        acc[tm][tn] = __builtin_amdgcn_mfma_f32_16x16x32_bf16(af[tm], bq[tn], acc[tm][tn], 0, 0, 0);
#pragma unroll
    for (int t2 = 0; t2 < 2; t2++)
#pragma unroll
      for (int tn2 = 0; tn2 < 2; tn2++)
        acc2[t2][tn2] = __builtin_amdgcn_mfma_f32_16x16x32_bf16(af2[t2], bp[tn2], acc2[t2][tn2], 0, 0, 0);
    __syncthreads();
  }
#pragma unroll
  for (int t2 = 0; t2 < 2; t2++)
#pragma unroll
    for (int tn2 = 0; tn2 < 2; tn2++)
#pragma unroll
      for (int r = 0; r < 4; r++)
        projF[(w * 32 + t2 * 16 + quad * 4 + r) * 32 + tn2 * 16 + lrow] = acc2[t2][tn2][r];
  {
    uint4 vr0 = *(const uint4*)((const char*)RwT + (long)(n0 + (p0 >> 6)) * 64 + (p0 & 63));
    uint4 vr1 = *(const uint4*)((const char*)RwT + (long)(n0 + (p1 >> 6)) * 64 + (p1 & 63));
    *(uint4*)((char*)Bt + p0) = vr0;
    *(uint4*)((char*)Bt + p1) = vr1;
  }
  __syncthreads();
  if (tid < 128) {
    float pr[32];
#pragma unroll
    for (int j = 0; j < 32; j++) pr[j] = projF[tid * 32 + j];
    float wo[32];
#pragma unroll
    for (int k = 0; k < 8; k++) { wo[k] = gl[k] * pr[8 + k]; wo[8 + k] = -gl[k] * pr[k]; }
#pragma unroll
    for (int kp = 0; kp < 8; kp++) {
      float sv = pr[16 + kp], tv = pr[24 + kp];
#pragma unroll
      for (int k = 0; k < 8; k++) {
        float gpb = gl[k] * pr[8 + k], gpa = gl[k] * pr[k];
        sv += gpb * Ml[k * 8 + kp]       - gpa * Ml[64 + k * 8 + kp];
        tv += gpb * Ml[128 + k * 8 + kp] - gpa * Ml[192 + k * 8 + kp];
      }
      wo[16 + kp] = gl[8 + kp] * sv;
      wo[24 + kp] = gl[16 + kp] * tv;
    }
#pragma unroll
    for (int j = 0; j < 32; j++) wLds[tid * 32 + j] = f2bf(wo[j]);
  }
  __syncthreads();
  {
    bf16x8 af[4], bq[4];
#pragma unroll
    for (int tm = 0; tm < 4; tm++)
      af[tm] = *(const bf16x8*)(wLds + (mw + tm * 16 + lrow) * 32 + quad * 8);
#pragma unroll
    for (int tn = 0; tn < 4; tn++)
      bq[tn] = *(const bf16x8*)(Bt + (nw + tn * 16 + lrow) * 32 + quad * 8);
#pragma unroll
    for (int tm = 0; tm < 4; tm++)
#pragma unroll
      for (int tn = 0; tn < 4; tn++)
        acc[tm][tn] = __builtin_amdgcn_mfma_f32_16x16x32_bf16(af[tm], bq[tn], acc[tm][tn], 0, 0, 0);
  }
#pragma unroll
  for (int tn = 0; tn < 4; tn++) {
    const int col = n0 + nw + tn * 16 + lrow;
    const float bias = bb[col];
#pragma unroll
    for (int tm = 0; tm < 4; tm++)
#pragma unroll
      for (int r = 0; r < 4; r++) {
        long row = m0 + mw + tm * 16 + quad * 4 + r;
        out[row * DD + col] = acc[tm][tn][r] + bias;
      }
  }
}

// ---------------------------------------------------------------------------
extern "C" void kernel_launch(void* const* d_in, const int* in_sizes, int n_in,
                              void* d_out, int out_size, void* d_ws, size_t ws_size,
                              hipStream_t stream) {
  const float* x   = (const float*)d_in[0];
  const float* Wb  = (const float*)d_in[1];
  const float* bb  = (const float*)d_in[2];
  const float* lng = (const float*)d_in[3];
  const float* lnb = (const float*)d_in[4];
  const float* Wc1 = (const float*)d_in[5];
  const float* bc1 = (const float*)d_in[6];
  const float* Wc2 = (const float*)d_in[7];
  const float* bc2 = (const float*)d_in[8];
  const float* Wrg = (const float*)d_in[9];
  const float* brg = (const float*)d_in[10];
  const float* Wrc = (const float*)d_in[11];
  const float* brc = (const float*)d_in[12];
  const float* Wsg = (const float*)d_in[13];
  const float* bsg = (const float*)d_in[14];
  const float* Wlc = (const float*)d_in[15];
  const float* blc = (const float*)d_in[16];
  const float* Us  = (const float*)d_in[17];
  const float* Vs  = (const float*)d_in[18];
  const float* Ul  = (const float*)d_in[19];
  const float* Vl  = (const float*)d_in[20];
  const float* Ao  = (const float*)d_in[21];
  const float* Bo  = (const float*)d_in[22];

  char* ws = (char*)d_ws;
  float* pooled = (float*)(ws + 0);         //  4*1024 f32  [memset]
  float* AWBW   = (float*)(ws + 16384);     // 16*1024 f32  [memset]
  float* h1pre  = (float*)(ws + 81920);     //  4*128 f32   [memset] -> 83968
  float* gates  = (float*)(ws + 83968);     //  4*32  f32   -> 84480
  float* Mbuf   = (float*)(ws + 84480);     //  256   f32   -> 85504
  u32*   cnt    = (u32*)  (ws + 85504);     //  counter [memset] -> 85568
  u16*   RwT    = (u16*)  (ws + 85568);     // 1024*32 bf16 -> 151104
  u16*   Pb     = (u16*)  (ws + 151104);    // 32*1024 bf16 -> 216640
  u16*   Wt     = (u16*)  (ws + 216640);    // 1024*1024 bf16 (2 MB) -> 2313792
  u16*   xb     = (u16*)  (ws + 2313792);   // 16384*1024 bf16 (32 MB), mode A
  float* out    = (float*)d_out;

  const bool modeA = ws_size >= (size_t)2313792 + 33554432;

  (void)hipMemsetAsync(d_ws, 0, 85568, stream);   // pooled+AWBW+h1pre+cnt
  if (modeA)
    k01_pre<true><<<552, 256, 0, stream>>>(x, xb, pooled, Wb, Ao, Bo, Us, Ul,
                                           AWBW, Mbuf, Pb, Wt);
  else
    k01_pre<false><<<552, 256, 0, stream>>>(x, xb, pooled, Wb, Ao, Bo, Us, Ul,
                                            AWBW, Mbuf, Pb, Wt);
  k2ab<<<40, 256, 0, stream>>>(pooled, lng, lnb, Wc1, h1pre,
                               AWBW, Vs, Vl, bc1, Wc2, bc2,
                               Wrg, brg, Wrc, brc, Wsg, bsg, Wlc, blc,
                               gates, RwT, cnt);
  if (modeA)
    k3a_fused<<<1024, 256, 0, stream>>>(xb, Wt, Pb, gates, Mbuf, RwT, bb, out);
  else
    k3_fused<false><<<1024, 256, 0, stream>>>(x, xb, Wt, Pb, gates, Mbuf, RwT, bb, out);
}